// Round 13
// baseline (77.837 us; speedup 1.0000x reference)
//
#include <hip/hip_runtime.h>
#include <hip/hip_fp16.h>

// Problem constants (B=2, H=8, L=1024, D=64)
#define N_HEADS 16          // B*H
#define L_SEQ   1024
#define D_HEAD  64
#define D2      128         // 2*D (sin/cos concat)
#define T_CHUNK 64
#define N_CHUNK (L_SEQ / T_CHUNK)   // 16
#define KV_ELEMS (D2 * D_HEAD)      // 8192 f16 values per chunk state
#define PK_UINTS (KV_ELEMS / 2)     // 4096 uint per chunk state

// f16 LDS pitches (elements). All chosen so fragment b64 reads are 8B-aligned
// and <=2-way banked; rows needing uint4 import/export are 16B-aligned.
#define P136 136   // q16/k16/s0t/k16row/ob: 272B rows = 17x16B
#define P76  76    // vt/pmat/vt1: 152B rows = 19x8B
#define P68  68    // k16t: 136B rows = 17x8B

#define SINCOS_SCALE 1.53398078788564122971e-3f   // (pi/2)/1024

typedef _Float16 f16_t;
typedef __attribute__((ext_vector_type(4))) _Float16 f16x4;
typedef __attribute__((ext_vector_type(4))) float f32x4;

__device__ __forceinline__ f32x4 mfma16(f16x4 a, f16x4 b, f32x4 c) {
    return __builtin_amdgcn_mfma_f32_16x16x16f16(a, b, c, 0, 0, 0);
}

// f16 pack helpers (storage only; accumulation stays f32)
__device__ __forceinline__ unsigned int packh2(float a, float b) {
    __half2 h = __floats2half2_rn(a, b);
    return __builtin_bit_cast(unsigned int, h);
}
__device__ __forceinline__ float2 unpackh2(unsigned int u) {
    __half2 h = __builtin_bit_cast(__half2, u);
    return __half22float2(h);
}

// All-VALU (DPP) reductions.
__device__ __forceinline__ float red8_dpp(float x) {
    x += __int_as_float(__builtin_amdgcn_mov_dpp(__float_as_int(x), 0xB1, 0xF, 0xF, true));
    x += __int_as_float(__builtin_amdgcn_mov_dpp(__float_as_int(x), 0x4E, 0xF, 0xF, true));
    x += __int_as_float(__builtin_amdgcn_mov_dpp(__float_as_int(x), 0x141, 0xF, 0xF, true));
    return x;
}
__device__ __forceinline__ float red16_dpp(float x) {
    x += __int_as_float(__builtin_amdgcn_mov_dpp(__float_as_int(x), 0xB1, 0xF, 0xF, true));
    x += __int_as_float(__builtin_amdgcn_mov_dpp(__float_as_int(x), 0x4E, 0xF, 0xF, true));
    x += __int_as_float(__builtin_amdgcn_mov_dpp(__float_as_int(x), 0x141, 0xF, 0xF, true));
    x += __int_as_float(__builtin_amdgcn_mov_dpp(__float_as_int(x), 0x140, 0xF, 0xF, true));
    return x;
}

// ---------------------------------------------------------------------------
// K1 (512 thr, grid 16x16): GEMM sumkv^T[m][d2] = V^T(64x64) . K_(64x128) on
// matrix cores (8 waves x 16 MFMA). Also exports the reweighted operands
// (kx = k_ [l][d2] f16, vx = V^T [m][l] f16) so K3 never re-reads k,v f32.
// ---------------------------------------------------------------------------
__global__ __launch_bounds__(512, 2) void k1_chunk_sums(
    const float* __restrict__ k, const float* __restrict__ v,
    unsigned int* __restrict__ sumkv, unsigned int* __restrict__ kx,
    unsigned int* __restrict__ vx, float* __restrict__ sumk)
{
    __shared__ __attribute__((aligned(16))) f16_t k16t[D2][P68];       // K_^T [d2][l]
    __shared__ __attribute__((aligned(16))) f16_t vt1[D_HEAD][P76];    // V^T  [m][l]
    __shared__ __attribute__((aligned(16))) f16_t k16row[T_CHUNK][P136]; // K_ [l][d2]
    __shared__ __attribute__((aligned(16))) f16_t ob[D_HEAD][P136];    // out [m][d2]
    __shared__ float s_tab[T_CHUNK], c_tab[T_CHUNK];

    const int c = blockIdx.x, n = blockIdx.y;
    const int tid = threadIdx.x;
    const int base = (n * L_SEQ + c * T_CHUNK) * D_HEAD;

    if (tid < T_CHUNK) {
        float th = SINCOS_SCALE * (float)(c * T_CHUNK + tid + 1);
        s_tab[tid] = __sinf(th);
        c_tab[tid] = __cosf(th);
    }
    __syncthreads();

    const float4* k4g = (const float4*)(k + base);
    const float4* v4g = (const float4*)(v + base);
#pragma unroll
    for (int j = 0; j < 2; ++j) {
        int i4 = j * 512 + tid;            // 0..1023
        int l = i4 >> 4, d = (i4 & 15) << 2;
        float4 kk = k4g[i4], vv = v4g[i4];
        kk.x = fmaxf(kk.x, 0.f); kk.y = fmaxf(kk.y, 0.f);
        kk.z = fmaxf(kk.z, 0.f); kk.w = fmaxf(kk.w, 0.f);
        vv.x = fmaxf(vv.x, 0.f); vv.y = fmaxf(vv.y, 0.f);
        vv.z = fmaxf(vv.z, 0.f); vv.w = fmaxf(vv.w, 0.f);
        float s = s_tab[l], cs = c_tab[l];
        f16_t a0 = (f16_t)(kk.x*s),  a1 = (f16_t)(kk.y*s),
              a2 = (f16_t)(kk.z*s),  a3 = (f16_t)(kk.w*s);
        f16_t b0 = (f16_t)(kk.x*cs), b1 = (f16_t)(kk.y*cs),
              b2 = (f16_t)(kk.z*cs), b3 = (f16_t)(kk.w*cs);
        k16t[d+0][l] = a0;  k16t[d+1][l] = a1;  k16t[d+2][l] = a2;  k16t[d+3][l] = a3;
        k16t[d+64][l] = b0; k16t[d+65][l] = b1; k16t[d+66][l] = b2; k16t[d+67][l] = b3;
        f16x4 ra; ra[0]=a0; ra[1]=a1; ra[2]=a2; ra[3]=a3;
        f16x4 rb; rb[0]=b0; rb[1]=b1; rb[2]=b2; rb[3]=b3;
        *(f16x4*)&k16row[l][d]      = ra;
        *(f16x4*)&k16row[l][d + 64] = rb;
        vt1[d+0][l] = (f16_t)vv.x; vt1[d+1][l] = (f16_t)vv.y;
        vt1[d+2][l] = (f16_t)vv.z; vt1[d+3][l] = (f16_t)vv.w;
    }
    __syncthreads();

    // sumk[d2] = sum_l K_[l][d2] (f32 accum over f16 values).
    if (tid < D2) {
        const f16x4* row = (const f16x4*)&k16t[tid][0];
        float acc = 0.f;
#pragma unroll
        for (int i = 0; i < 16; ++i) {
            f16x4 x = row[i];
            acc += ((float)x[0] + (float)x[1]) + ((float)x[2] + (float)x[3]);
        }
        sumk[(n * N_CHUNK + c) * D2 + tid] = acc;
    }

    // Export reweighted operands for K3 (coalesced).
    {
        uint4* kxd = (uint4*)kx + (size_t)(n * L_SEQ + c * T_CHUNK) * 16; // 16 uint4/row
#pragma unroll
        for (int t = 0; t < 2; ++t) {
            int u = t * 512 + tid;         // 0..1023
            kxd[u] = *(const uint4*)&k16row[u >> 4][(u & 15) * 8];
        }
        uint2* vxd = (uint2*)vx + (size_t)(n * N_CHUNK + c) * 1024;
#pragma unroll
        for (int t = 0; t < 2; ++t) {
            int u = t * 512 + tid;
            vxd[u] = *(const uint2*)&vt1[u >> 4][(u & 15) * 4];
        }
    }

    // GEMM: D[m][d2], A = V^T rows, B^T = K_^T rows. K=64 (4 ks steps).
    const int wave = tid >> 6, lane = tid & 63;
    const int fr = lane & 15, fk = (lane >> 4) << 2;
    const int mt = wave >> 1, ntg = (wave & 1) * 4;

    f32x4 acc[4];
#pragma unroll
    for (int t = 0; t < 4; ++t) acc[t] = (f32x4){0.f, 0.f, 0.f, 0.f};
#pragma unroll
    for (int ks = 0; ks < 4; ++ks) {
        f16x4 a = *(const f16x4*)&vt1[mt * 16 + fr][ks * 16 + fk];
#pragma unroll
        for (int t = 0; t < 4; ++t) {
            f16x4 b = *(const f16x4*)&k16t[(ntg + t) * 16 + fr][ks * 16 + fk];
            acc[t] = mfma16(a, b, acc[t]);
        }
    }
#pragma unroll
    for (int t = 0; t < 4; ++t)
#pragma unroll
        for (int r = 0; r < 4; ++r)
            ob[mt * 16 + fk + r][(ntg + t) * 16 + fr] = (f16_t)acc[t][r];
    __syncthreads();

    uint4* dst = (uint4*)sumkv + (size_t)(n * N_CHUNK + c) * 1024;
#pragma unroll
    for (int t = 0; t < 2; ++t) {
        int u = t * 512 + tid;
        dst[u] = *(const uint4*)&ob[u >> 4][(u & 15) * 8];
    }
}

// ---------------------------------------------------------------------------
// K2: exclusive prefix over 16 chunks. Packed f16 storage, f32 accumulation.
// ---------------------------------------------------------------------------
__global__ __launch_bounds__(256) void k2_prefix(
    unsigned int* __restrict__ sumkv, float* __restrict__ sumk)
{
    const int x = blockIdx.x, n = blockIdx.y;
    const int tid = threadIdx.x;

    if (x < 8) {
        uint2* base = (uint2*)(sumkv + (size_t)n * N_CHUNK * PK_UINTS) + x * 256 + tid;
        uint2 t[N_CHUNK];
#pragma unroll
        for (int c = 0; c < N_CHUNK; ++c) t[c] = base[c * (PK_UINTS / 2)];
        float r0 = 0.f, r1 = 0.f, r2 = 0.f, r3 = 0.f;
#pragma unroll
        for (int c = 0; c < N_CHUNK; ++c) {
            uint2 cur = t[c];
            base[c * (PK_UINTS / 2)] = make_uint2(packh2(r0, r1), packh2(r2, r3));
            float2 lo = unpackh2(cur.x), hi = unpackh2(cur.y);
            r0 += lo.x; r1 += lo.y; r2 += hi.x; r3 += hi.y;
        }
    } else if (tid < D2) {
        float* bk = sumk + n * N_CHUNK * D2 + tid;
        float t[N_CHUNK];
#pragma unroll
        for (int c = 0; c < N_CHUNK; ++c) t[c] = bk[c * D2];
        float r = 0.f;
#pragma unroll
        for (int c = 0; c < N_CHUNK; ++c) { bk[c * D2] = r; r += t[c]; }
    }
}

// ---------------------------------------------------------------------------
// K3 (512 thr, grid 16x16): S = Q_ K_^T (64x64 causal, 4x4 tiles, skips
// upper tiles), O = Q_ S0 + P V, den = q.kc0 + rowsum(masked S).
// k_/V^T imported pre-reweighted f16 from K1 (kx/vx) -- no k,v f32 re-read.
// ---------------------------------------------------------------------------
__global__ __launch_bounds__(512, 2) void k3_output(
    const float* __restrict__ q, const unsigned int* __restrict__ kx,
    const unsigned int* __restrict__ vx, const unsigned int* __restrict__ sumkv,
    const float* __restrict__ sumk, float* __restrict__ out)
{
    __shared__ __attribute__((aligned(16))) f16_t q16[T_CHUNK][P136];
    __shared__ __attribute__((aligned(16))) f16_t k16[T_CHUNK][P136];
    __shared__ __attribute__((aligned(16))) f16_t vt[D_HEAD][P76];    // V^T [m][l]
    __shared__ __attribute__((aligned(16))) f16_t s0t[D_HEAD][P136];  // S0^T [m][d2]
    __shared__ __attribute__((aligned(16))) f16_t pmat[T_CHUNK][P76]; // P [l][l']
    __shared__ float kc0[D2];
    __shared__ float den0_s[T_CHUNK], dp[2][T_CHUNK], rden[T_CHUNK];
    __shared__ float s_tab[T_CHUNK], c_tab[T_CHUNK];

    const int c = blockIdx.x, n = blockIdx.y;
    const int tid = threadIdx.x;
    const int base = (n * L_SEQ + c * T_CHUNK) * D_HEAD;

    if (tid < T_CHUNK) {
        float th = SINCOS_SCALE * (float)(c * T_CHUNK + tid + 1);
        s_tab[tid] = __sinf(th);
        c_tab[tid] = __cosf(th);
    }
    __syncthreads();

    // Stage q (f32 -> reweighted f16).
    const float4* q4g = (const float4*)(q + base);
#pragma unroll
    for (int j = 0; j < 2; ++j) {
        int i4 = j * 512 + tid;
        int l = i4 >> 4, d = (i4 & 15) << 2;
        float4 qq = q4g[i4];
        qq.x = fmaxf(qq.x, 0.f); qq.y = fmaxf(qq.y, 0.f);
        qq.z = fmaxf(qq.z, 0.f); qq.w = fmaxf(qq.w, 0.f);
        float s = s_tab[l], cs = c_tab[l];
        q16[l][d+0]  = (f16_t)(qq.x*s);  q16[l][d+1]  = (f16_t)(qq.y*s);
        q16[l][d+2]  = (f16_t)(qq.z*s);  q16[l][d+3]  = (f16_t)(qq.w*s);
        q16[l][d+64] = (f16_t)(qq.x*cs); q16[l][d+65] = (f16_t)(qq.y*cs);
        q16[l][d+66] = (f16_t)(qq.z*cs); q16[l][d+67] = (f16_t)(qq.w*cs);
    }
    // Import k_ (pre-reweighted), V^T, S0^T -- raw copies.
    {
        const uint4* kxs = (const uint4*)kx + (size_t)(n * L_SEQ + c * T_CHUNK) * 16;
#pragma unroll
        for (int t = 0; t < 2; ++t) {
            int u = t * 512 + tid;
            *(uint4*)&k16[u >> 4][(u & 15) * 8] = kxs[u];
        }
        const uint2* vxs = (const uint2*)vx + (size_t)(n * N_CHUNK + c) * 1024;
#pragma unroll
        for (int t = 0; t < 2; ++t) {
            int u = t * 512 + tid;
            *(uint2*)&vt[u >> 4][(u & 15) * 4] = vxs[u];
        }
        const uint4* pkv = (const uint4*)sumkv + (size_t)(n * N_CHUNK + c) * 1024;
#pragma unroll
        for (int t = 0; t < 2; ++t) {
            int u = t * 512 + tid;
            *(uint4*)&s0t[u >> 4][(u & 15) * 8] = pkv[u];
        }
    }
    if (tid < D2) kc0[tid] = sumk[(n * N_CHUNK + c) * D2 + tid];
    __syncthreads();

    // den0[l] = q_[l] . kc0 (8 lanes per row).
    {
        int l = tid >> 3, seg = (tid & 7) << 4;
        float a = 0.f;
#pragma unroll
        for (int i = 0; i < 16; ++i) a += (float)q16[l][seg + i] * kc0[seg + i];
        a = red8_dpp(a);
        if ((tid & 7) == 0) den0_s[l] = a;
    }

    const int wave = tid >> 6, lane = tid & 63;
    const int fr = lane & 15, fk = (lane >> 4) << 2, rowq = fk;
    const int mt = wave >> 1;
    const int nt0 = (wave & 1) << 1;

    // S phase: 4x4 causal tiles, 2 per wave; upper (mt<nt) tiles are zero.
    {
        float rs[4] = {0.f, 0.f, 0.f, 0.f};
#pragma unroll
        for (int t = 0; t < 2; ++t) {
            int nt = nt0 + t;
            if (mt >= nt) {
                f32x4 sa = {0.f, 0.f, 0.f, 0.f};
#pragma unroll
                for (int ks = 0; ks < 8; ++ks) {
                    f16x4 a = *(const f16x4*)&q16[mt * 16 + fr][ks * 16 + fk];
                    f16x4 b = *(const f16x4*)&k16[nt * 16 + fr][ks * 16 + fk];
                    sa = mfma16(a, b, sa);
                }
#pragma unroll
                for (int r = 0; r < 4; ++r) {
                    int row = rowq + r;
                    float mv = (mt > nt || fr <= row) ? sa[r] : 0.f;  // causal
                    pmat[mt * 16 + row][nt * 16 + fr] = (f16_t)mv;
                    rs[r] += red16_dpp(mv);
                }
            } else {
#pragma unroll
                for (int r = 0; r < 4; ++r)
                    pmat[mt * 16 + rowq + r][nt * 16 + fr] = (f16_t)0.f;
            }
        }
        if (fr == 0)
#pragma unroll
            for (int r = 0; r < 4; ++r) dp[wave & 1][mt * 16 + rowq + r] = rs[r];
    }
    __syncthreads();

    if (tid < T_CHUNK)
        rden[tid] = 1.f / fmaxf(den0_s[tid] + dp[0][tid] + dp[1][tid], 1e-6f);

    // O phase: O = Q_@S0 (K=128) + P@V (K=64); 4x4 tiles, 2 per wave.
    f32x4 o0 = {0.f, 0.f, 0.f, 0.f}, o1 = {0.f, 0.f, 0.f, 0.f};
#pragma unroll
    for (int ks = 0; ks < 8; ++ks) {
        f16x4 a  = *(const f16x4*)&q16[mt * 16 + fr][ks * 16 + fk];
        f16x4 b0 = *(const f16x4*)&s0t[(nt0 + 0) * 16 + fr][ks * 16 + fk];
        f16x4 b1 = *(const f16x4*)&s0t[(nt0 + 1) * 16 + fr][ks * 16 + fk];
        o0 = mfma16(a, b0, o0);
        o1 = mfma16(a, b1, o1);
    }
#pragma unroll
    for (int ks = 0; ks < 4; ++ks) {
        f16x4 a  = *(const f16x4*)&pmat[mt * 16 + fr][ks * 16 + fk];
        f16x4 b0 = *(const f16x4*)&vt[(nt0 + 0) * 16 + fr][ks * 16 + fk];
        f16x4 b1 = *(const f16x4*)&vt[(nt0 + 1) * 16 + fr][ks * 16 + fk];
        o0 = mfma16(a, b0, o0);
        o1 = mfma16(a, b1, o1);
    }
    __syncthreads();   // rden ready

    float* og = out + base;
#pragma unroll
    for (int r = 0; r < 4; ++r) {
        int row = mt * 16 + rowq + r;
        float rd = rden[row];
        og[row * D_HEAD + (nt0 + 0) * 16 + fr] = o0[r] * rd;
        og[row * D_HEAD + (nt0 + 1) * 16 + fr] = o1[r] * rd;
    }
}

// ---------------------------------------------------------------------------
extern "C" void kernel_launch(void* const* d_in, const int* in_sizes, int n_in,
                              void* d_out, int out_size, void* d_ws, size_t ws_size,
                              hipStream_t stream) {
    (void)in_sizes; (void)n_in; (void)out_size; (void)ws_size;
    const float* q = (const float*)d_in[0];
    const float* k = (const float*)d_in[1];
    const float* v = (const float*)d_in[2];
    float* out = (float*)d_out;

    unsigned int* sumkv = (unsigned int*)d_ws;                 // f16 [N][C][m][d2] : 4 MB
    unsigned int* kx    = sumkv + (size_t)N_HEADS * N_CHUNK * PK_UINTS;   // f16 [N][L][d2] : 4 MB
    unsigned int* vx    = kx + (size_t)N_HEADS * L_SEQ * D2 / 2;          // f16 [N][C][m][l] : 2 MB
    float*        sumk  = (float*)(vx + (size_t)N_HEADS * N_CHUNK * T_CHUNK * D_HEAD / 2);

    dim3 grid(N_CHUNK, N_HEADS);
    k1_chunk_sums<<<grid, 512, 0, stream>>>(k, v, sumkv, kx, vx, sumk);
    dim3 grid2(9, N_HEADS);
    k2_prefix<<<grid2, 256, 0, stream>>>(sumkv, sumk);
    k3_output<<<grid, 512, 0, stream>>>(q, kx, vx, sumkv, sumk, out);
}

// Round 14
// 75.136 us; speedup vs baseline: 1.0360x; 1.0360x over previous
//
#include <hip/hip_runtime.h>
#include <hip/hip_fp16.h>

// Problem constants (B=2, H=8, L=1024, D=64)
#define N_HEADS 16          // B*H
#define L_SEQ   1024
#define D_HEAD  64
#define D2      128         // 2*D (sin/cos concat)
#define T_CHUNK 32
#define N_CHUNK (L_SEQ / T_CHUNK)   // 32
#define KV_ELEMS (D2 * D_HEAD)      // 8192 f16 values per chunk
#define PK_UINTS (KV_ELEMS / 2)     // 4096 packed half2 per chunk

// f16 LDS pitches (elements):
#define PQ 132   // q16/k16 [32][PQ]   (264B rows, conflict-free frag reads)
#define PS 136   // s0t/ob  [64][PS]   (272B rows = 17x16B: uint4-aligned)
#define PV 36    // vt/k16t/pmat       (72B rows, conflict-free frag reads)

#define SINCOS_SCALE 1.53398078788564122971e-3f   // (pi/2)/1024

typedef _Float16 f16_t;
typedef __attribute__((ext_vector_type(4))) _Float16 f16x4;
typedef __attribute__((ext_vector_type(4))) float f32x4;

__device__ __forceinline__ f32x4 mfma16(f16x4 a, f16x4 b, f32x4 c) {
    return __builtin_amdgcn_mfma_f32_16x16x16f16(a, b, c, 0, 0, 0);
}

// f16 pack helpers (storage only; accumulation stays f32)
__device__ __forceinline__ unsigned int packh2(float a, float b) {
    __half2 h = __floats2half2_rn(a, b);
    return __builtin_bit_cast(unsigned int, h);
}
__device__ __forceinline__ float2 unpackh2(unsigned int u) {
    __half2 h = __builtin_bit_cast(__half2, u);
    return __half22float2(h);
}

// All-VALU (DPP) reductions.
__device__ __forceinline__ float red8_dpp(float x) {
    x += __int_as_float(__builtin_amdgcn_mov_dpp(__float_as_int(x), 0xB1, 0xF, 0xF, true));
    x += __int_as_float(__builtin_amdgcn_mov_dpp(__float_as_int(x), 0x4E, 0xF, 0xF, true));
    x += __int_as_float(__builtin_amdgcn_mov_dpp(__float_as_int(x), 0x141, 0xF, 0xF, true));
    return x;
}
__device__ __forceinline__ float red16_dpp(float x) {
    x += __int_as_float(__builtin_amdgcn_mov_dpp(__float_as_int(x), 0xB1, 0xF, 0xF, true));
    x += __int_as_float(__builtin_amdgcn_mov_dpp(__float_as_int(x), 0x4E, 0xF, 0xF, true));
    x += __int_as_float(__builtin_amdgcn_mov_dpp(__float_as_int(x), 0x141, 0xF, 0xF, true));
    x += __int_as_float(__builtin_amdgcn_mov_dpp(__float_as_int(x), 0x140, 0xF, 0xF, true));
    return x;
}

// ---------------------------------------------------------------------------
// K1: sumkv^T[m][d2] = sum_l V^T[m][l] K_[l][d2]  -- a 64x128, K=32 GEMM on
// matrix cores. A = V^T (vt rows), B^T = K_^T (k16t rows). 4 waves (mt=wave)
// x 8 N-tiles x 2 K-steps = 64 MFMAs/block. Output bounced via LDS for
// coalesced uint4 stores in the [m][d2] flat layout K3 consumes.
// ---------------------------------------------------------------------------
__global__ __launch_bounds__(256, 2) void k1_chunk_sums(
    const float* __restrict__ k, const float* __restrict__ v,
    unsigned int* __restrict__ sumkv, float* __restrict__ sumk)
{
    __shared__ __attribute__((aligned(16))) f16_t k16t[D2][PV];     // K_^T [d2][l]
    __shared__ __attribute__((aligned(16))) f16_t vt1[D_HEAD][PV];  // V^T  [m][l]
    __shared__ __attribute__((aligned(16))) f16_t ob[D_HEAD][PS];   // out  [m][d2]
    __shared__ float s_tab[T_CHUNK], c_tab[T_CHUNK];

    const int c = blockIdx.x, n = blockIdx.y;
    const int tid = threadIdx.x;
    const int base = (n * L_SEQ + c * T_CHUNK) * D_HEAD;

    if (tid < T_CHUNK) {
        float th = SINCOS_SCALE * (float)(c * T_CHUNK + tid + 1);
        s_tab[tid] = __sinf(th);
        c_tab[tid] = __cosf(th);
    }
    __syncthreads();

    // Stage: relu + reweight, transposed f16 into LDS.
    const float4* k4g = (const float4*)(k + base);
    const float4* v4g = (const float4*)(v + base);
#pragma unroll
    for (int j = 0; j < 2; ++j) {
        int i4 = j * 256 + tid;            // 0..511
        int l = i4 >> 4, d = (i4 & 15) << 2;
        float4 kk = k4g[i4], vv = v4g[i4];
        kk.x = fmaxf(kk.x, 0.f); kk.y = fmaxf(kk.y, 0.f);
        kk.z = fmaxf(kk.z, 0.f); kk.w = fmaxf(kk.w, 0.f);
        vv.x = fmaxf(vv.x, 0.f); vv.y = fmaxf(vv.y, 0.f);
        vv.z = fmaxf(vv.z, 0.f); vv.w = fmaxf(vv.w, 0.f);
        float s = s_tab[l], cs = c_tab[l];
        k16t[d+0][l]    = (f16_t)(kk.x*s);  k16t[d+1][l]    = (f16_t)(kk.y*s);
        k16t[d+2][l]    = (f16_t)(kk.z*s);  k16t[d+3][l]    = (f16_t)(kk.w*s);
        k16t[d+64][l]   = (f16_t)(kk.x*cs); k16t[d+65][l]   = (f16_t)(kk.y*cs);
        k16t[d+66][l]   = (f16_t)(kk.z*cs); k16t[d+67][l]   = (f16_t)(kk.w*cs);
        vt1[d+0][l] = (f16_t)vv.x; vt1[d+1][l] = (f16_t)vv.y;
        vt1[d+2][l] = (f16_t)vv.z; vt1[d+3][l] = (f16_t)vv.w;
    }
    __syncthreads();

    // sumk[d2] = sum_l k16t[d2][l] (f32 accum over f16 values).
    if (tid < D2) {
        const f16x4* row = (const f16x4*)&k16t[tid][0];
        float acc = 0.f;
#pragma unroll
        for (int i = 0; i < 8; ++i) {
            f16x4 x = row[i];
            acc += ((float)x[0] + (float)x[1]) + ((float)x[2] + (float)x[3]);
        }
        sumk[(n * N_CHUNK + c) * D2 + tid] = acc;
    }

    const int wave = tid >> 6, lane = tid & 63;
    const int fr = lane & 15;            // A/B fragment row (m or d2 within tile)
    const int fk = (lane >> 4) << 2;     // fragment K offset; also D row base

    // A fragments (V^T rows, fixed mt = wave), K=32 in two steps.
    f16x4 a0 = *(const f16x4*)&vt1[wave * 16 + fr][fk];
    f16x4 a1 = *(const f16x4*)&vt1[wave * 16 + fr][16 + fk];

    f32x4 acc[8];
#pragma unroll
    for (int nt = 0; nt < 8; ++nt) acc[nt] = (f32x4){0.f, 0.f, 0.f, 0.f};
#pragma unroll
    for (int nt = 0; nt < 8; ++nt) {
        f16x4 b0 = *(const f16x4*)&k16t[nt * 16 + fr][fk];
        f16x4 b1 = *(const f16x4*)&k16t[nt * 16 + fr][16 + fk];
        acc[nt] = mfma16(a0, b0, acc[nt]);
        acc[nt] = mfma16(a1, b1, acc[nt]);
    }

    // D (row=m, col=d2) -> LDS bounce (f16), then coalesced uint4 store.
#pragma unroll
    for (int nt = 0; nt < 8; ++nt)
#pragma unroll
        for (int r = 0; r < 4; ++r)
            ob[wave * 16 + fk + r][nt * 16 + fr] = (f16_t)acc[nt][r];
    __syncthreads();

    uint4* dst = (uint4*)(sumkv + (size_t)(n * N_CHUNK + c) * PK_UINTS);
#pragma unroll
    for (int t = 0; t < 4; ++t) {
        int u = t * 256 + tid;             // 0..1023; flat f16 = m*128 + 8*(u&15)
        dst[u] = *(const uint4*)&ob[u >> 4][(u & 15) * 8];
    }
}

// ---------------------------------------------------------------------------
// K2: exclusive prefix over chunks. Packed f16 storage, f32 accumulation.
// Layout-agnostic (elementwise over the flat buffer). Verbatim R9/R11.
// ---------------------------------------------------------------------------
__global__ __launch_bounds__(256) void k2_prefix(
    unsigned int* __restrict__ sumkv, float* __restrict__ sumk)
{
    const int x = blockIdx.x, n = blockIdx.y;
    const int tid = threadIdx.x;

    if (x < 8) {
        uint2* base = (uint2*)(sumkv + (size_t)n * N_CHUNK * PK_UINTS) + x * 256 + tid;
        uint2 t[N_CHUNK];
#pragma unroll
        for (int c = 0; c < N_CHUNK; ++c) t[c] = base[c * (PK_UINTS / 2)];
        float r0 = 0.f, r1 = 0.f, r2 = 0.f, r3 = 0.f;
#pragma unroll
        for (int c = 0; c < N_CHUNK; ++c) {
            uint2 cur = t[c];
            base[c * (PK_UINTS / 2)] = make_uint2(packh2(r0, r1), packh2(r2, r3));
            float2 lo = unpackh2(cur.x), hi = unpackh2(cur.y);
            r0 += lo.x; r1 += lo.y; r2 += hi.x; r3 += hi.y;
        }
    } else if (tid < D2) {
        float* bk = sumk + n * N_CHUNK * D2 + tid;
        float t[N_CHUNK];
#pragma unroll
        for (int c = 0; c < N_CHUNK; ++c) t[c] = bk[c * D2];
        float r = 0.f;
#pragma unroll
        for (int c = 0; c < N_CHUNK; ++c) { bk[c * D2] = r; r += t[c]; }
    }
}

// ---------------------------------------------------------------------------
// K3: MFMA chunked linear attention. Verbatim R11 (proven at 79.0 us).
// ---------------------------------------------------------------------------
__global__ __launch_bounds__(256, 2) void k3_output(
    const float* __restrict__ q, const float* __restrict__ k,
    const float* __restrict__ v, const unsigned int* __restrict__ sumkv,
    const float* __restrict__ sumk, float* __restrict__ out)
{
    __shared__ __attribute__((aligned(16))) f16_t q16[T_CHUNK][PQ];
    __shared__ __attribute__((aligned(16))) f16_t k16[T_CHUNK][PQ];
    __shared__ __attribute__((aligned(16))) f16_t vt[D_HEAD][PV];   // V^T [m][l]
    __shared__ __attribute__((aligned(16))) f16_t s0t[D_HEAD][PS];  // S0^T [m][d2]
    __shared__ __attribute__((aligned(16))) f16_t pmat[T_CHUNK][PV];// P [l][l']
    __shared__ float kc0[D2];
    __shared__ float den0_s[T_CHUNK], dpA[T_CHUNK], dpB[T_CHUNK], rden[T_CHUNK];
    __shared__ float s_tab[T_CHUNK], c_tab[T_CHUNK];

    const int c = blockIdx.x, n = blockIdx.y;
    const int tid = threadIdx.x;
    const int base = (n * L_SEQ + c * T_CHUNK) * D_HEAD;

    if (tid < T_CHUNK) {
        float th = SINCOS_SCALE * (float)(c * T_CHUNK + tid + 1);
        s_tab[tid] = __sinf(th);
        c_tab[tid] = __cosf(th);
    }
    __syncthreads();

    // ---- Stage q_/k_ (row-major f16), V^T, S0^T, kc0 ----
    const float4* q4g = (const float4*)(q + base);
    const float4* k4g = (const float4*)(k + base);
    const float4* v4g = (const float4*)(v + base);
#pragma unroll
    for (int j = 0; j < 2; ++j) {
        int i4 = j * 256 + tid;
        int l = i4 >> 4, d = (i4 & 15) << 2;
        float4 kk = k4g[i4], qq = q4g[i4], vv = v4g[i4];
        kk.x = fmaxf(kk.x, 0.f); kk.y = fmaxf(kk.y, 0.f);
        kk.z = fmaxf(kk.z, 0.f); kk.w = fmaxf(kk.w, 0.f);
        qq.x = fmaxf(qq.x, 0.f); qq.y = fmaxf(qq.y, 0.f);
        qq.z = fmaxf(qq.z, 0.f); qq.w = fmaxf(qq.w, 0.f);
        vv.x = fmaxf(vv.x, 0.f); vv.y = fmaxf(vv.y, 0.f);
        vv.z = fmaxf(vv.z, 0.f); vv.w = fmaxf(vv.w, 0.f);
        float s = s_tab[l], cs = c_tab[l];
        q16[l][d+0]    = (f16_t)(qq.x*s);  q16[l][d+1]    = (f16_t)(qq.y*s);
        q16[l][d+2]    = (f16_t)(qq.z*s);  q16[l][d+3]    = (f16_t)(qq.w*s);
        q16[l][d+64]   = (f16_t)(qq.x*cs); q16[l][d+65]   = (f16_t)(qq.y*cs);
        q16[l][d+66]   = (f16_t)(qq.z*cs); q16[l][d+67]   = (f16_t)(qq.w*cs);
        k16[l][d+0]    = (f16_t)(kk.x*s);  k16[l][d+1]    = (f16_t)(kk.y*s);
        k16[l][d+2]    = (f16_t)(kk.z*s);  k16[l][d+3]    = (f16_t)(kk.w*s);
        k16[l][d+64]   = (f16_t)(kk.x*cs); k16[l][d+65]   = (f16_t)(kk.y*cs);
        k16[l][d+66]   = (f16_t)(kk.z*cs); k16[l][d+67]   = (f16_t)(kk.w*cs);
        vt[d+0][l] = (f16_t)vv.x; vt[d+1][l] = (f16_t)vv.y;
        vt[d+2][l] = (f16_t)vv.z; vt[d+3][l] = (f16_t)vv.w;
    }
    {
        const uint4* pkv = (const uint4*)(sumkv + (size_t)(n * N_CHUNK + c) * PK_UINTS);
#pragma unroll
        for (int jj = 0; jj < 4; ++jj) {
            int u = jj * 256 + tid;
            int pos = u << 3;                       // flat f16 index
            *(uint4*)&s0t[pos >> 7][pos & 127] = pkv[u];
        }
    }
    if (tid < D2) kc0[tid] = sumk[(n * N_CHUNK + c) * D2 + tid];
    __syncthreads();

    // ---- den0[l] = q_[l] . kc0 (all threads; 8 lanes per row) ----
    {
        int l = tid >> 3, seg = (tid & 7) << 4;
        float a = 0.f;
#pragma unroll
        for (int i = 0; i < 16; ++i) a += (float)q16[l][seg + i] * kc0[seg + i];
        a = red8_dpp(a);
        if ((tid & 7) == 0) den0_s[l] = a;
    }

    const int wave = tid >> 6, lane = tid & 63;
    const int fr = lane & 15;            // fragment row/col (lane%16)
    const int fk = (lane >> 4) << 2;     // fragment k offset
    const int rowq = (lane >> 4) << 2;   // C/D row base

    // ---- S phase: tiles (0,0),(1,0),(1,1); (0,1) is fully masked ----
    if (wave < 3) {
        const int mt = (wave == 0) ? 0 : 1;
        const int nt = (wave == 2) ? 1 : 0;
        f32x4 sa = {0.f, 0.f, 0.f, 0.f};
#pragma unroll
        for (int ks = 0; ks < 8; ++ks) {
            f16x4 a = *(const f16x4*)&q16[mt * 16 + fr][ks * 16 + fk];
            f16x4 b = *(const f16x4*)&k16[nt * 16 + fr][ks * 16 + fk];
            sa = mfma16(a, b, sa);
        }
#pragma unroll
        for (int r = 0; r < 4; ++r) {
            int row = rowq + r;
            float mv = (mt > nt || fr <= row) ? sa[r] : 0.f;   // causal: l' <= l
            pmat[mt * 16 + row][nt * 16 + fr] = (f16_t)mv;
            float rs = red16_dpp(mv);
            if (fr == 0) {
                if (wave == 2) dpB[16 + row] = rs;
                else dpA[mt * 16 + row] = rs;
            }
        }
    } else {
        // zero P tile (0,1): rows 0..15, cols 16..31
        int row = lane >> 2, colb = 16 + ((lane & 3) << 2);
        *(uint2*)&pmat[row][colb] = make_uint2(0u, 0u);
    }
    __syncthreads();

    if (tid < T_CHUNK) {
        float den = den0_s[tid] + dpA[tid] + ((tid >= 16) ? dpB[tid] : 0.f);
        rden[tid] = 1.f / fmaxf(den, 1e-6f);
    }

    // ---- O phase: O = Q_ @ S0 + P @ V ; 2x4 tiles, 2 per wave ----
    const int mt = wave >> 1;
    const int nt0 = (wave & 1) << 1, nt1 = nt0 + 1;
    f32x4 o0 = {0.f, 0.f, 0.f, 0.f}, o1 = {0.f, 0.f, 0.f, 0.f};
#pragma unroll
    for (int ks = 0; ks < 8; ++ks) {
        f16x4 a  = *(const f16x4*)&q16[mt * 16 + fr][ks * 16 + fk];
        f16x4 b0 = *(const f16x4*)&s0t[nt0 * 16 + fr][ks * 16 + fk];
        f16x4 b1 = *(const f16x4*)&s0t[nt1 * 16 + fr][ks * 16 + fk];
        o0 = mfma16(a, b0, o0);
        o1 = mfma16(a, b1, o1);
    }
#pragma unroll
    for (int ks = 0; ks < 2; ++ks) {
        f16x4 a  = *(const f16x4*)&pmat[mt * 16 + fr][ks * 16 + fk];
        f16x4 b0 = *(const f16x4*)&vt[nt0 * 16 + fr][ks * 16 + fk];
        f16x4 b1 = *(const f16x4*)&vt[nt1 * 16 + fr][ks * 16 + fk];
        o0 = mfma16(a, b0, o0);
        o1 = mfma16(a, b1, o1);
    }
    __syncthreads();   // rden ready

    float* og = out + base;
#pragma unroll
    for (int r = 0; r < 4; ++r) {
        int row = mt * 16 + rowq + r;
        float rd = rden[row];
        og[row * D_HEAD + nt0 * 16 + fr] = o0[r] * rd;
        og[row * D_HEAD + nt1 * 16 + fr] = o1[r] * rd;
    }
}

// ---------------------------------------------------------------------------
extern "C" void kernel_launch(void* const* d_in, const int* in_sizes, int n_in,
                              void* d_out, int out_size, void* d_ws, size_t ws_size,
                              hipStream_t stream) {
    (void)in_sizes; (void)n_in; (void)out_size; (void)ws_size;
    const float* q = (const float*)d_in[0];
    const float* k = (const float*)d_in[1];
    const float* v = (const float*)d_in[2];
    float* out = (float*)d_out;

    unsigned int* sumkv = (unsigned int*)d_ws;                         // packed f16 [N][C][m][d2]
    float* sumk = (float*)(sumkv + (size_t)N_HEADS * N_CHUNK * PK_UINTS); // f32 [N][C][128]

    dim3 grid(N_CHUNK, N_HEADS);
    k1_chunk_sums<<<grid, 256, 0, stream>>>(k, v, sumkv, sumk);
    dim3 grid2(9, N_HEADS);
    k2_prefix<<<grid2, 256, 0, stream>>>(sumkv, sumk);
    k3_output<<<grid, 256, 0, stream>>>(q, k, v, sumkv, sumk, out);
}